// Round 14
// baseline (256.761 us; speedup 1.0000x reference)
//
#include <hip/hip_runtime.h>
#include <stdint.h>

// GaitnetActor B=8192, OPT=16. Round 14: R12 revert + 2-launch structure.
// k_front (714 blocks): blocks 0-511 compute cse[16 elems] reading fp32
// weights with inline RNE bf16 cvt (bit-identical to convert-then-load);
// blocks 512-713 convert k_main's weights to bf16 in ws. k_main unchanged
// from R12 (135 us). bf16 MFMA / fp32 accum.
// out[0:131072]=logits fp32, [131072:262144]=duration fp32.

static constexpr int B_ = 8192;

typedef __attribute__((ext_vector_type(8))) short bf16x8;
typedef __attribute__((ext_vector_type(4))) float f32x4;

__device__ __forceinline__ float u2f(uint16_t u) {
    union { uint32_t i; float f; } c; c.i = (uint32_t)u << 16; return c.f;
}
__device__ __forceinline__ uint16_t f2u(float f) {
    union { float f; uint32_t i; } c; c.f = f;
    uint32_t x = c.i;
    return (uint16_t)((x + 0x7FFFu + ((x >> 16) & 1u)) >> 16);
}
__device__ __forceinline__ bf16x8 cvt8(float4 a, float4 b) {
    bf16x8 r;
    r[0] = (short)f2u(a.x); r[1] = (short)f2u(a.y);
    r[2] = (short)f2u(a.z); r[3] = (short)f2u(a.w);
    r[4] = (short)f2u(b.x); r[5] = (short)f2u(b.y);
    r[6] = (short)f2u(b.z); r[7] = (short)f2u(b.w);
    return r;
}

// ws layout (uint16 elems)
static constexpr size_t WCSE   = 0;                    // bf16 [8192][512]
static constexpr size_t WTW1UE = 4194304;              // bf16 [512][128]
static constexpr size_t WTW2   = WTW1UE + 65536;       // bf16 [256][512]
static constexpr size_t WUW2   = WTW2 + 131072;        // bf16 [128][128]
static constexpr size_t WUW1B  = WUW2 + 16384;         // bf16 [128][32] 0-pad

// ---------------- k_front: cse blocks (0-511) + conv blocks (512-713) ------
__global__ __launch_bounds__(512) void k_front(
    const float* __restrict__ obs,
    const float* __restrict__ sw1, const float* __restrict__ sb1,
    const float* __restrict__ sw2, const float* __restrict__ sb2,
    const float* __restrict__ uw1,
    const float* __restrict__ uw2,
    const float* __restrict__ tw1, const float* __restrict__ tb1,
    const float* __restrict__ tw2,
    uint16_t* __restrict__ ws)
{
    const int t = threadIdx.x;

    if (blockIdx.x >= 512) {
        // ---- conv role: 202 blocks x 512 float4s = 103424 ----
        int i4 = (blockIdx.x - 512) * 512 + t;
        if (i4 >= 102400) {                      // uw1b: zero-padded K=32
            int q = i4 - 102400;                 // [0,1024)
            int n = q >> 3, k0 = (q & 7) * 4;
            ushort4 o = {0, 0, 0, 0};
            if (k0 < 8) {
                float4 v = *reinterpret_cast<const float4*>(uw1 + n * 8 + k0);
                o.x = f2u(v.x); o.y = f2u(v.y); o.z = f2u(v.z); o.w = f2u(v.w);
            }
            *reinterpret_cast<ushort4*>(ws + WUW1B + n * 32 + k0) = o;
            return;
        }
        const float* src; size_t dst;
        if (i4 < 16384) {                        // tw1 ue-part (k>=256)
            int n = i4 >> 5, w = i4 & 31;
            src = tw1 + (size_t)n * 384 + 256 + w * 4;
            dst = WTW1UE + (size_t)n * 128 + w * 4;
        } else if (i4 < 49152) {
            int q = (i4 - 16384) * 4;
            src = tw2 + q; dst = WTW2 + q;
        } else if (i4 < 53248) {
            int q = (i4 - 49152) * 4;
            src = uw2 + q; dst = WUW2 + q;
        } else {
            return;                              // 53248..102400 unused range
        }
        float4 v = *reinterpret_cast<const float4*>(src);
        ushort4 o;
        o.x = f2u(v.x); o.y = f2u(v.y); o.z = f2u(v.z); o.w = f2u(v.w);
        *reinterpret_cast<ushort4*>(ws + dst) = o;
        return;
    }

    // ---- cse role: 16 batch elems, fp32 weights + inline cvt ----
    __shared__ float xs[16][24];
    __shared__ uint16_t h1s[16 * 264];
    __shared__ uint16_t seL[16 * 264];
    const int b0 = blockIdx.x * 16;

    if (t < 352) {
        int e = t / 22, c = t - e * 22;
        xs[e][c] = obs[(size_t)(b0 + e) * 150 + c];
    }
    __syncthreads();
    {   // shared L1 (VALU): neuron t&255, 8 elems each
        const int n = t & 255;
        float w[22];
        #pragma unroll
        for (int k = 0; k < 22; ++k) w[k] = sw1[n * 22 + k];
        const float bias = sb1[n];
        #pragma unroll
        for (int ii = 0; ii < 8; ++ii) {
            int e = (t >> 8) * 8 + ii;
            float a = bias;
            #pragma unroll
            for (int k = 0; k < 22; ++k) a += w[k] * xs[e][k];
            h1s[e * 264 + n] = f2u(fmaxf(a, 0.f));
        }
    }
    __syncthreads();
    const int wv = t >> 6, lane = t & 63, quad = lane >> 4, l16 = lane & 15;
    {   // shared L2 (MFMA): M=16, wave N=32, K=256 -> seL (B = fp32 + cvt8)
        f32x4 acc[2];
        #pragma unroll
        for (int nt = 0; nt < 2; ++nt) {
            float bv = sb2[wv * 32 + nt * 16 + l16];
            acc[nt] = {bv, bv, bv, bv};
        }
        #pragma unroll
        for (int kk = 0; kk < 8; ++kk) {
            bf16x8 af = *reinterpret_cast<const bf16x8*>(
                &h1s[l16 * 264 + kk * 32 + quad * 8]);
            #pragma unroll
            for (int nt = 0; nt < 2; ++nt) {
                const float* wr = sw2 + (size_t)(wv * 32 + nt * 16 + l16) * 256
                                  + kk * 32 + quad * 8;
                bf16x8 bf = cvt8(*reinterpret_cast<const float4*>(wr),
                                 *reinterpret_cast<const float4*>(wr + 4));
                acc[nt] = __builtin_amdgcn_mfma_f32_16x16x32_bf16(
                    af, bf, acc[nt], 0, 0, 0);
            }
        }
        #pragma unroll
        for (int nt = 0; nt < 2; ++nt)
            #pragma unroll
            for (int r = 0; r < 4; ++r)
                seL[(quad * 4 + r) * 264 + wv * 32 + nt * 16 + l16] =
                    f2u(fmaxf(acc[nt][r], 0.f));
    }
    __syncthreads();
    {   // cse (MFMA): M=16, wave N=64, K=256, no relu (B = fp32 + cvt8)
        f32x4 acc[4];
        #pragma unroll
        for (int nt = 0; nt < 4; ++nt) {
            float bv = tb1[wv * 64 + nt * 16 + l16];
            acc[nt] = {bv, bv, bv, bv};
        }
        #pragma unroll
        for (int kk = 0; kk < 8; ++kk) {
            bf16x8 af = *reinterpret_cast<const bf16x8*>(
                &seL[l16 * 264 + kk * 32 + quad * 8]);
            #pragma unroll
            for (int nt = 0; nt < 4; ++nt) {
                const float* wr = tw1 + (size_t)(wv * 64 + nt * 16 + l16) * 384
                                  + kk * 32 + quad * 8;     // k<256: se-part
                bf16x8 bf = cvt8(*reinterpret_cast<const float4*>(wr),
                                 *reinterpret_cast<const float4*>(wr + 4));
                acc[nt] = __builtin_amdgcn_mfma_f32_16x16x32_bf16(
                    af, bf, acc[nt], 0, 0, 0);
            }
        }
        #pragma unroll
        for (int nt = 0; nt < 4; ++nt)
            #pragma unroll
            for (int r = 0; r < 4; ++r)
                ws[WCSE + (size_t)(b0 + quad * 4 + r) * 512 +
                   wv * 64 + nt * 16 + l16] = f2u(acc[nt][r]);
    }
}

// ---------------- k_main (identical to R12) --------------------------------
static constexpr int UQB_OFF  = 0;
static constexpr int NOOP_OFF = 5120;
static constexpr int CSE_OFF  = 5376;
static constexpr int H1U_OFF  = 9472;
static constexpr int UET_OFF  = 26880;
static constexpr int H1T_OFF  = 44288;
static constexpr int SMEM_SZ  = 78080;

__global__ __launch_bounds__(512, 4) void k_main(
    const float* __restrict__ obs,
    const float* __restrict__ ub1,
    const float* __restrict__ ub2, const float* __restrict__ emb,
    const float* __restrict__ tb2,
    const float* __restrict__ vw,  const float* __restrict__ vb,
    const float* __restrict__ dw,  const float* __restrict__ db,
    const uint16_t* __restrict__ wsb,
    float* __restrict__ out)
{
    __shared__ __align__(16) char smem[SMEM_SZ];
    uint16_t* uqb   = (uint16_t*)(smem + UQB_OFF);
    float*    noopf = (float*)(smem + NOOP_OFF);
    uint16_t* cseL  = (uint16_t*)(smem + CSE_OFF);
    uint16_t* h1u   = (uint16_t*)(smem + H1U_OFF);
    uint16_t* uet   = (uint16_t*)(smem + UET_OFF);
    uint16_t* h1t   = (uint16_t*)(smem + H1T_OFF);
    uint16_t* t2    = h1t;

    const int t    = threadIdx.x;
    const int wv   = t >> 6;
    const int lane = t & 63;
    const int quad = lane >> 4;
    const int l16  = lane & 15;
    const int b0   = blockIdx.x * 4;

    const uint16_t* csep  = wsb + WCSE;
    const uint16_t* tw1ue = wsb + WTW1UE;
    const uint16_t* tw2b  = wsb + WTW2;
    const uint16_t* uw2b  = wsb + WUW2;
    const uint16_t* uw1b  = wsb + WUW1B;

    // ---- stage 1: uqb bf16 [64][40] (K=32 zero-padded), noop, cse rows ----
    {
        int r = t >> 3, q = t & 7;
        int e = r >> 4, o = r & 15;
        ushort4 ov = {0, 0, 0, 0};
        if (q < 2) {
            const float2* sp = reinterpret_cast<const float2*>(
                &obs[(size_t)(b0 + e) * 150 + 22 + o * 8 + q * 4]);
            float2 a = sp[0], b = sp[1];
            ov.x = f2u(a.x); ov.y = f2u(a.y); ov.z = f2u(b.x); ov.w = f2u(b.y);
        }
        *reinterpret_cast<ushort4*>(&uqb[r * 40 + q * 4]) = ov;
        #pragma unroll
        for (int ii = 0; ii < 2; ++ii) {
            int i = t + ii * 512;
            int ee = i >> 8, cc = i & 255;
            ((uint32_t*)cseL)[ee * 256 + cc] =
                ((const uint32_t*)(csep + (size_t)(b0 + ee) * 512))[cc];
        }
        if (t < 64) {
            int ee = t >> 4, oo = t & 15;
            noopf[t] = (obs[(size_t)(b0 + ee) * 150 + 22 + oo * 8] == 1.0f) ? 1.0f : 0.0f;
        }
    }
    __syncthreads();

    // ---- stage 2: unique L1 via MFMA (wave: M=64 x N=16, K=32) ----
    {
        const int n = wv * 16 + l16;
        const float bv = ub1[n];
        f32x4 acc[4];
        #pragma unroll
        for (int mt = 0; mt < 4; ++mt) acc[mt] = {bv, bv, bv, bv};
        bf16x8 bf = *reinterpret_cast<const bf16x8*>(&uw1b[n * 32 + quad * 8]);
        #pragma unroll
        for (int mt = 0; mt < 4; ++mt) {
            bf16x8 af = *reinterpret_cast<const bf16x8*>(
                &uqb[(mt * 16 + l16) * 40 + quad * 8]);
            acc[mt] = __builtin_amdgcn_mfma_f32_16x16x32_bf16(af, bf, acc[mt], 0, 0, 0);
        }
        #pragma unroll
        for (int mt = 0; mt < 4; ++mt)
            #pragma unroll
            for (int r = 0; r < 4; ++r) {
                int row = mt * 16 + quad * 4 + r;
                h1u[row * 136 + n] = f2u(fmaxf(acc[mt][r], 0.f));
            }
    }
    __syncthreads();

    // ---- stage 3: unique L2 via MFMA (wave: M=64 x N=16), K=128 -> uet ----
    {
        const int n = wv * 16 + l16;
        const float bv = ub2[n];
        const float ev = emb[n];
        f32x4 acc[4];
        #pragma unroll
        for (int mt = 0; mt < 4; ++mt) acc[mt] = {bv, bv, bv, bv};
        #pragma unroll
        for (int kk = 0; kk < 4; ++kk) {
            bf16x8 bf = *reinterpret_cast<const bf16x8*>(
                &uw2b[(size_t)n * 128 + kk * 32 + quad * 8]);
            #pragma unroll
            for (int mt = 0; mt < 4; ++mt) {
                bf16x8 af = *reinterpret_cast<const bf16x8*>(
                    &h1u[(mt * 16 + l16) * 136 + kk * 32 + quad * 8]);
                acc[mt] = __builtin_amdgcn_mfma_f32_16x16x32_bf16(af, bf, acc[mt], 0, 0, 0);
            }
        }
        #pragma unroll
        for (int mt = 0; mt < 4; ++mt)
            #pragma unroll
            for (int r = 0; r < 4; ++r) {
                int row = mt * 16 + quad * 4 + r;
                float v = (noopf[row] != 0.0f) ? ev : fmaxf(acc[mt][r], 0.f);
                uet[row * 136 + n] = f2u(v);
            }
    }
    __syncthreads();

    // ---- trunk: 2 N-chunks of 256; L1 (K=128, acc init = cse) -> L2 ----
    f32x4 acc2[4][2];
    #pragma unroll
    for (int nt = 0; nt < 2; ++nt) {
        float bv = tb2[wv * 32 + nt * 16 + l16];
        #pragma unroll
        for (int mt = 0; mt < 4; ++mt) acc2[mt][nt] = {bv, bv, bv, bv};
    }

    #pragma unroll
    for (int nc = 0; nc < 2; ++nc) {
        {
            f32x4 acc1[4][2];
            #pragma unroll
            for (int nt = 0; nt < 2; ++nt) {
                int n = nc * 256 + wv * 32 + nt * 16 + l16;
                #pragma unroll
                for (int mt = 0; mt < 4; ++mt) {
                    float v = u2f(cseL[mt * 512 + n]);
                    acc1[mt][nt] = {v, v, v, v};
                }
            }
            const uint16_t* bb = tw1ue + (size_t)(nc * 256 + wv * 32 + l16) * 128
                                 + quad * 8;
            bf16x8 bc[2], bn[2];
            bc[0] = *reinterpret_cast<const bf16x8*>(bb);
            bc[1] = *reinterpret_cast<const bf16x8*>(bb + 2048);
            #pragma unroll
            for (int kk = 0; kk < 4; ++kk) {
                if (kk < 3) {
                    bn[0] = *reinterpret_cast<const bf16x8*>(bb + (kk + 1) * 32);
                    bn[1] = *reinterpret_cast<const bf16x8*>(bb + 2048 + (kk + 1) * 32);
                }
                bf16x8 af[4];
                #pragma unroll
                for (int mt = 0; mt < 4; ++mt)
                    af[mt] = *reinterpret_cast<const bf16x8*>(
                        &uet[(mt * 16 + l16) * 136 + kk * 32 + quad * 8]);
                #pragma unroll
                for (int mt = 0; mt < 4; ++mt)
                    #pragma unroll
                    for (int nt = 0; nt < 2; ++nt)
                        acc1[mt][nt] = __builtin_amdgcn_mfma_f32_16x16x32_bf16(
                            af[mt], bc[nt], acc1[mt][nt], 0, 0, 0);
                bc[0] = bn[0]; bc[1] = bn[1];
            }
            #pragma unroll
            for (int mt = 0; mt < 4; ++mt)
                #pragma unroll
                for (int nt = 0; nt < 2; ++nt)
                    #pragma unroll
                    for (int r = 0; r < 4; ++r) {
                        int row = mt * 16 + quad * 4 + r;
                        h1t[row * 264 + wv * 32 + nt * 16 + l16] =
                            f2u(fmaxf(acc1[mt][nt][r], 0.f));
                    }
        }
        __syncthreads();
        {
            const uint16_t* cb = tw2b + (size_t)(wv * 32 + l16) * 512 + nc * 256
                                 + quad * 8;
            bf16x8 cc[2], cn[2];
            cc[0] = *reinterpret_cast<const bf16x8*>(cb);
            cc[1] = *reinterpret_cast<const bf16x8*>(cb + 8192);
            #pragma unroll
            for (int k2 = 0; k2 < 8; ++k2) {
                if (k2 < 7) {
                    cn[0] = *reinterpret_cast<const bf16x8*>(cb + (k2 + 1) * 32);
                    cn[1] = *reinterpret_cast<const bf16x8*>(cb + 8192 + (k2 + 1) * 32);
                }
                bf16x8 af[4];
                #pragma unroll
                for (int mt = 0; mt < 4; ++mt)
                    af[mt] = *reinterpret_cast<const bf16x8*>(
                        &h1t[(mt * 16 + l16) * 264 + k2 * 32 + quad * 8]);
                #pragma unroll
                for (int mt = 0; mt < 4; ++mt)
                    #pragma unroll
                    for (int nt = 0; nt < 2; ++nt)
                        acc2[mt][nt] = __builtin_amdgcn_mfma_f32_16x16x32_bf16(
                            af[mt], cc[nt], acc2[mt][nt], 0, 0, 0);
                cc[0] = cn[0]; cc[1] = cn[1];
            }
        }
        if (nc == 0) __syncthreads();
    }
    __syncthreads();
    #pragma unroll
    for (int mt = 0; mt < 4; ++mt)
        #pragma unroll
        for (int nt = 0; nt < 2; ++nt)
            #pragma unroll
            for (int r = 0; r < 4; ++r) {
                int row = mt * 16 + quad * 4 + r;
                t2[row * 264 + wv * 32 + nt * 16 + l16] =
                    f2u(fmaxf(acc2[mt][nt][r], 0.f));
            }
    __syncthreads();

    // ---- heads ----
    {
        float vwf[4], dwf[4];
        #pragma unroll
        for (int j = 0; j < 4; ++j) {
            vwf[j] = vw[lane + 64 * j];
            dwf[j] = dw[lane + 64 * j];
        }
        const float vbf = vb[0], dbf = db[0];
        #pragma unroll
        for (int rr = 0; rr < 8; ++rr) {
            int row = wv * 8 + rr;
            float sv = 0.f, sd = 0.f;
            #pragma unroll
            for (int j = 0; j < 4; ++j) {
                float tv = u2f(t2[row * 264 + lane + 64 * j]);
                sv += tv * vwf[j];
                sd += tv * dwf[j];
            }
            #pragma unroll
            for (int off = 32; off > 0; off >>= 1) {
                sv += __shfl_down(sv, off);
                sd += __shfl_down(sd, off);
            }
            if (lane == 0) {
                int g = blockIdx.x * 64 + row;
                out[g] = sv + vbf;
                float z = sd + dbf;
                float sig = 1.f / (1.f + __expf(-z));
                out[B_ * 16 + g] = sig * 0.4f + 0.1f;
            }
        }
    }
}

extern "C" void kernel_launch(void* const* d_in, const int* in_sizes, int n_in,
                              void* d_out, int out_size, void* d_ws, size_t ws_size,
                              hipStream_t stream) {
    const float* obs = (const float*)d_in[0];
    const float* sw1 = (const float*)d_in[1];
    const float* sb1 = (const float*)d_in[2];
    const float* sw2 = (const float*)d_in[3];
    const float* sb2 = (const float*)d_in[4];
    const float* uw1 = (const float*)d_in[5];
    const float* ub1 = (const float*)d_in[6];
    const float* uw2 = (const float*)d_in[7];
    const float* ub2 = (const float*)d_in[8];
    const float* emb = (const float*)d_in[9];
    const float* tw1 = (const float*)d_in[10];
    const float* tb1 = (const float*)d_in[11];
    const float* tw2 = (const float*)d_in[12];
    const float* tb2 = (const float*)d_in[13];
    const float* vw  = (const float*)d_in[14];
    const float* vb  = (const float*)d_in[15];
    const float* dw  = (const float*)d_in[16];
    const float* db  = (const float*)d_in[17];

    uint16_t* wsb = (uint16_t*)d_ws;

    k_front<<<714, 512, 0, stream>>>(obs, sw1, sb1, sw2, sb2,
                                     uw1, uw2, tw1, tb1, tw2, wsb);
    k_main<<<B_ / 4, 512, 0, stream>>>(obs, ub1, ub2, emb, tb2,
                                       vw, vb, dw, db, wsb, (float*)d_out);
}

// Round 15
// 254.569 us; speedup vs baseline: 1.0086x; 1.0086x over previous
//
#include <hip/hip_runtime.h>
#include <stdint.h>

// GaitnetActor B=8192, OPT=16. Round 15: attack LDS-read throughput.
// k_main: M=128/block (8 elems), 512 thr (8 waves), 1 blk/CU. Trunk-L2
// wave tile M=64 x N=64 (nt=4): each A-fragment LDS read feeds 4 MFMAs
// (L2 A-traffic/FLOP halved vs R12). h1t double-buffered, 4 N-chunks of
// 128. k_cse: M=32/block, 256 blocks. k_conv = R12. bf16 MFMA/fp32 acc.
// out[0:131072]=logits fp32, [131072:262144]=duration fp32.

static constexpr int B_ = 8192;

typedef __attribute__((ext_vector_type(8))) short bf16x8;
typedef __attribute__((ext_vector_type(4))) float f32x4;

__device__ __forceinline__ float u2f(uint16_t u) {
    union { uint32_t i; float f; } c; c.i = (uint32_t)u << 16; return c.f;
}
__device__ __forceinline__ uint16_t f2u(float f) {
    union { float f; uint32_t i; } c; c.f = f;
    uint32_t x = c.i;
    return (uint16_t)((x + 0x7FFFu + ((x >> 16) & 1u)) >> 16);
}

// ws layout (uint16 elems) — identical to R12
static constexpr size_t WCSE   = 0;                    // bf16 [8192][512]
static constexpr size_t WTW1SE = 4194304;              // bf16 [512][256]
static constexpr size_t WTW1UE = WTW1SE + 131072;      // bf16 [512][128]
static constexpr size_t WTW2   = WTW1UE + 65536;       // bf16 [256][512]
static constexpr size_t WUW2   = WTW2 + 131072;        // bf16 [128][128]
static constexpr size_t WSW2   = WUW2 + 16384;         // bf16 [256][256]
static constexpr size_t WUW1B  = WSW2 + 65536;         // bf16 [128][32] 0-pad

// ---------------- k_conv: identical to R12 (404 blocks) --------------------
__global__ __launch_bounds__(256) void k_conv(
    const float* __restrict__ tw1, const float* __restrict__ tw2,
    const float* __restrict__ uw2, const float* __restrict__ sw2,
    const float* __restrict__ uw1, uint16_t* __restrict__ ws)
{
    int i4 = blockIdx.x * 256 + threadIdx.x;
    if (i4 >= 102400) {
        int q = i4 - 102400;
        int n = q >> 3, k0 = (q & 7) * 4;
        ushort4 o = {0, 0, 0, 0};
        if (k0 < 8) {
            float4 v = *reinterpret_cast<const float4*>(uw1 + n * 8 + k0);
            o.x = f2u(v.x); o.y = f2u(v.y); o.z = f2u(v.z); o.w = f2u(v.w);
        }
        *reinterpret_cast<ushort4*>(ws + WUW1B + n * 32 + k0) = o;
        return;
    }
    const float* src; size_t dst;
    if (i4 < 32768) {
        int g = i4 * 4, n = g >> 8, k = g & 255;
        src = tw1 + (size_t)n * 384 + k;
        dst = WTW1SE + (size_t)g;
    } else if (i4 < 49152) {
        int q = i4 - 32768, n = q >> 5, w = q & 31;
        src = tw1 + (size_t)n * 384 + 256 + w * 4;
        dst = WTW1UE + (size_t)n * 128 + w * 4;
    } else if (i4 < 81920) {
        int q = (i4 - 49152) * 4;
        src = tw2 + q; dst = WTW2 + q;
    } else if (i4 < 86016) {
        int q = (i4 - 81920) * 4;
        src = uw2 + q; dst = WUW2 + q;
    } else {
        int q = (i4 - 86016) * 4;
        src = sw2 + q; dst = WSW2 + q;
    }
    float4 v = *reinterpret_cast<const float4*>(src);
    ushort4 o;
    o.x = f2u(v.x); o.y = f2u(v.y); o.z = f2u(v.z); o.w = f2u(v.w);
    *reinterpret_cast<ushort4*>(ws + dst) = o;
}

// ---------------- k_cse: M=32 elems/block, 256 blocks, 512 thr -------------
__global__ __launch_bounds__(512) void k_cse(
    const float* __restrict__ obs,
    const float* __restrict__ sw1, const float* __restrict__ sb1,
    const float* __restrict__ sb2, const float* __restrict__ tb1,
    uint16_t* __restrict__ ws)
{
    __shared__ float xs[32][24];
    __shared__ uint16_t h1s[32 * 264];
    __shared__ uint16_t seL[32 * 264];
    const int t = threadIdx.x;
    const int b0 = blockIdx.x * 32;
    const uint16_t* sw2b   = ws + WSW2;
    const uint16_t* tw1seb = ws + WTW1SE;

    for (int i = t; i < 704; i += 512) {
        int e = i / 22, c = i - e * 22;
        xs[e][c] = obs[(size_t)(b0 + e) * 150 + c];
    }
    __syncthreads();
    {   // shared L1 (VALU): neuron t&255, 16 elems each
        const int n = t & 255;
        float w[22];
        #pragma unroll
        for (int k = 0; k < 22; ++k) w[k] = sw1[n * 22 + k];
        const float bias = sb1[n];
        #pragma unroll
        for (int ii = 0; ii < 16; ++ii) {
            int e = (t >> 8) * 16 + ii;
            float a = bias;
            #pragma unroll
            for (int k = 0; k < 22; ++k) a += w[k] * xs[e][k];
            h1s[e * 264 + n] = f2u(fmaxf(a, 0.f));
        }
    }
    __syncthreads();
    const int wv = t >> 6, lane = t & 63, quad = lane >> 4, l16 = lane & 15;
    {   // shared L2 (MFMA): M=32 (2 mt), wave N=32, K=256 -> seL
        f32x4 acc[2][2];
        #pragma unroll
        for (int nt = 0; nt < 2; ++nt) {
            float bv = sb2[wv * 32 + nt * 16 + l16];
            acc[0][nt] = {bv, bv, bv, bv};
            acc[1][nt] = {bv, bv, bv, bv};
        }
        const uint16_t* bb = sw2b + (size_t)(wv * 32 + l16) * 256 + quad * 8;
        bf16x8 bc[2], bn[2];
        bc[0] = *reinterpret_cast<const bf16x8*>(bb);
        bc[1] = *reinterpret_cast<const bf16x8*>(bb + 4096);
        #pragma unroll
        for (int kk = 0; kk < 8; ++kk) {
            if (kk < 7) {
                bn[0] = *reinterpret_cast<const bf16x8*>(bb + (kk + 1) * 32);
                bn[1] = *reinterpret_cast<const bf16x8*>(bb + 4096 + (kk + 1) * 32);
            }
            bf16x8 af[2];
            #pragma unroll
            for (int mt = 0; mt < 2; ++mt)
                af[mt] = *reinterpret_cast<const bf16x8*>(
                    &h1s[(mt * 16 + l16) * 264 + kk * 32 + quad * 8]);
            #pragma unroll
            for (int mt = 0; mt < 2; ++mt)
                #pragma unroll
                for (int nt = 0; nt < 2; ++nt)
                    acc[mt][nt] = __builtin_amdgcn_mfma_f32_16x16x32_bf16(
                        af[mt], bc[nt], acc[mt][nt], 0, 0, 0);
            bc[0] = bn[0]; bc[1] = bn[1];
        }
        #pragma unroll
        for (int mt = 0; mt < 2; ++mt)
            #pragma unroll
            for (int nt = 0; nt < 2; ++nt)
                #pragma unroll
                for (int r = 0; r < 4; ++r)
                    seL[(mt * 16 + quad * 4 + r) * 264 + wv * 32 + nt * 16 + l16] =
                        f2u(fmaxf(acc[mt][nt][r], 0.f));
    }
    __syncthreads();
    {   // cse (MFMA): M=32 (2 mt), wave N=64 (4 nt), K=256, no relu -> ws
        f32x4 acc[2][4];
        #pragma unroll
        for (int nt = 0; nt < 4; ++nt) {
            float bv = tb1[wv * 64 + nt * 16 + l16];
            acc[0][nt] = {bv, bv, bv, bv};
            acc[1][nt] = {bv, bv, bv, bv};
        }
        const uint16_t* bb = tw1seb + (size_t)(wv * 64 + l16) * 256 + quad * 8;
        bf16x8 bc[4], bn[4];
        #pragma unroll
        for (int nt = 0; nt < 4; ++nt)
            bc[nt] = *reinterpret_cast<const bf16x8*>(bb + nt * 4096);
        #pragma unroll
        for (int kk = 0; kk < 8; ++kk) {
            if (kk < 7) {
                #pragma unroll
                for (int nt = 0; nt < 4; ++nt)
                    bn[nt] = *reinterpret_cast<const bf16x8*>(
                        bb + nt * 4096 + (kk + 1) * 32);
            }
            bf16x8 af[2];
            #pragma unroll
            for (int mt = 0; mt < 2; ++mt)
                af[mt] = *reinterpret_cast<const bf16x8*>(
                    &seL[(mt * 16 + l16) * 264 + kk * 32 + quad * 8]);
            #pragma unroll
            for (int mt = 0; mt < 2; ++mt)
                #pragma unroll
                for (int nt = 0; nt < 4; ++nt)
                    acc[mt][nt] = __builtin_amdgcn_mfma_f32_16x16x32_bf16(
                        af[mt], bc[nt], acc[mt][nt], 0, 0, 0);
            #pragma unroll
            for (int nt = 0; nt < 4; ++nt) bc[nt] = bn[nt];
        }
        #pragma unroll
        for (int mt = 0; mt < 2; ++mt)
            #pragma unroll
            for (int nt = 0; nt < 4; ++nt)
                #pragma unroll
                for (int r = 0; r < 4; ++r)
                    ws[WCSE + (size_t)(b0 + mt * 16 + quad * 4 + r) * 512 +
                       wv * 64 + nt * 16 + l16] = f2u(acc[mt][nt][r]);
    }
}

// ---------------- k_main: M=128/block, N=64 L2 wave tiles ------------------
// LDS (bytes): uqb u16[128][40]=10240 | noop f32[128] @10240 | cse
// bf16[8][512] @10752 (8192) | uet u16[128][136] @18944 | h1tA @53760 |
// h1tB @88576 -> 123392 B (1 blk/CU). h1u overlays h1tA; t2 [128][264]
// overlays uet+h1tA after the main loop.
static constexpr int UQB_OFF  = 0;
static constexpr int NOOP_OFF = 10240;
static constexpr int CSE_OFF  = 10752;
static constexpr int UET_OFF  = 18944;
static constexpr int H1TA_OFF = 53760;
static constexpr int H1TB_OFF = 88576;
static constexpr int SMEM_SZ  = 123392;

__global__ __launch_bounds__(512, 2) void k_main(
    const float* __restrict__ obs,
    const float* __restrict__ ub1,
    const float* __restrict__ ub2, const float* __restrict__ emb,
    const float* __restrict__ tb2,
    const float* __restrict__ vw,  const float* __restrict__ vb,
    const float* __restrict__ dw,  const float* __restrict__ db,
    const uint16_t* __restrict__ wsb,
    float* __restrict__ out)
{
    __shared__ __align__(16) char smem[SMEM_SZ];
    uint16_t* uqb   = (uint16_t*)(smem + UQB_OFF);
    float*    noopf = (float*)(smem + NOOP_OFF);
    uint16_t* cseL  = (uint16_t*)(smem + CSE_OFF);
    uint16_t* uet   = (uint16_t*)(smem + UET_OFF);
    uint16_t* h1ta  = (uint16_t*)(smem + H1TA_OFF);
    uint16_t* h1tb  = (uint16_t*)(smem + H1TB_OFF);
    uint16_t* h1u   = h1ta;                     // overlay (dead before h1tA)
    uint16_t* t2    = uet;                      // overlay after main loop

    const int t    = threadIdx.x;
    const int wv   = t >> 6;                    // 0..7
    const int lane = t & 63;
    const int quad = lane >> 4;
    const int l16  = lane & 15;
    const int mh   = wv >> 2;                   // M-half 0..1
    const int ng   = wv & 3;                    // N-group 0..3
    const int b0   = blockIdx.x * 8;

    const uint16_t* csep  = wsb + WCSE;
    const uint16_t* tw1ue = wsb + WTW1UE;
    const uint16_t* tw2b  = wsb + WTW2;
    const uint16_t* uw2b  = wsb + WUW2;
    const uint16_t* uw1b  = wsb + WUW1B;

    // ---- stage 1: uqb bf16 [128][40] (cols 0..31), noop, cse rows ----
    {
        #pragma unroll
        for (int ii = 0; ii < 2; ++ii) {
            int idx = t + ii * 512;
            int r = idx >> 3, q = idx & 7;
            int e = r >> 4, o = r & 15;
            ushort4 ov = {0, 0, 0, 0};
            if (q < 2) {
                const float2* sp = reinterpret_cast<const float2*>(
                    &obs[(size_t)(b0 + e) * 150 + 22 + o * 8 + q * 4]);
                float2 a = sp[0], b = sp[1];
                ov.x = f2u(a.x); ov.y = f2u(a.y); ov.z = f2u(b.x); ov.w = f2u(b.y);
            }
            *reinterpret_cast<ushort4*>(&uqb[r * 40 + q * 4]) = ov;
        }
        #pragma unroll
        for (int ii = 0; ii < 4; ++ii) {        // cse: 2048 dwords
            int i = t + ii * 512;
            int ee = i >> 8, cc = i & 255;
            ((uint32_t*)cseL)[ee * 256 + cc] =
                ((const uint32_t*)(csep + (size_t)(b0 + ee) * 512))[cc];
        }
        if (t < 128) {
            int ee = t >> 4, oo = t & 15;
            noopf[t] = (obs[(size_t)(b0 + ee) * 150 + 22 + oo * 8] == 1.0f) ? 1.0f : 0.0f;
        }
    }
    __syncthreads();

    // ---- stage 2: unique L1 via MFMA (wave: M=64 x N=32, K=32) ----
    {
        f32x4 acc[4][2];
        #pragma unroll
        for (int nt = 0; nt < 2; ++nt) {
            float bv = ub1[ng * 32 + nt * 16 + l16];
            #pragma unroll
            for (int mt = 0; mt < 4; ++mt) acc[mt][nt] = {bv, bv, bv, bv};
        }
        bf16x8 bf[2];
        #pragma unroll
        for (int nt = 0; nt < 2; ++nt)
            bf[nt] = *reinterpret_cast<const bf16x8*>(
                &uw1b[(ng * 32 + nt * 16 + l16) * 32 + quad * 8]);
        #pragma unroll
        for (int mt = 0; mt < 4; ++mt) {
            bf16x8 af = *reinterpret_cast<const bf16x8*>(
                &uqb[(mh * 64 + mt * 16 + l16) * 40 + quad * 8]);
            #pragma unroll
            for (int nt = 0; nt < 2; ++nt)
                acc[mt][nt] = __builtin_amdgcn_mfma_f32_16x16x32_bf16(
                    af, bf[nt], acc[mt][nt], 0, 0, 0);
        }
        #pragma unroll
        for (int mt = 0; mt < 4; ++mt)
            #pragma unroll
            for (int nt = 0; nt < 2; ++nt)
                #pragma unroll
                for (int r = 0; r < 4; ++r) {
                    int row = mh * 64 + mt * 16 + quad * 4 + r;
                    h1u[row * 136 + ng * 32 + nt * 16 + l16] =
                        f2u(fmaxf(acc[mt][nt][r], 0.f));
                }
    }
    __syncthreads();

    // ---- stage 3: unique L2 via MFMA (wave: M=64 x N=32, K=128) -> uet ----
    {
        f32x4 acc[4][2];
        float ev[2];
        #pragma unroll
        for (int nt = 0; nt < 2; ++nt) {
            int n = ng * 32 + nt * 16 + l16;
            float bv = ub2[n];
            ev[nt] = emb[n];
            #pragma unroll
            for (int mt = 0; mt < 4; ++mt) acc[mt][nt] = {bv, bv, bv, bv};
        }
        const uint16_t* bb = uw2b + (size_t)(ng * 32 + l16) * 128 + quad * 8;
        bf16x8 bc[2], bn[2];
        bc[0] = *reinterpret_cast<const bf16x8*>(bb);
        bc[1] = *reinterpret_cast<const bf16x8*>(bb + 2048);
        #pragma unroll
        for (int kk = 0; kk < 4; ++kk) {
            if (kk < 3) {
                bn[0] = *reinterpret_cast<const bf16x8*>(bb + (kk + 1) * 32);
                bn[1] = *reinterpret_cast<const bf16x8*>(bb + 2048 + (kk + 1) * 32);
            }
            bf16x8 af[4];
            #pragma unroll
            for (int mt = 0; mt < 4; ++mt)
                af[mt] = *reinterpret_cast<const bf16x8*>(
                    &h1u[(mh * 64 + mt * 16 + l16) * 136 + kk * 32 + quad * 8]);
            #pragma unroll
            for (int mt = 0; mt < 4; ++mt)
                #pragma unroll
                for (int nt = 0; nt < 2; ++nt)
                    acc[mt][nt] = __builtin_amdgcn_mfma_f32_16x16x32_bf16(
                        af[mt], bc[nt], acc[mt][nt], 0, 0, 0);
            bc[0] = bn[0]; bc[1] = bn[1];
        }
        __syncthreads();                        // h1u reads done (h1tA overlay)
        #pragma unroll
        for (int mt = 0; mt < 4; ++mt)
            #pragma unroll
            for (int nt = 0; nt < 2; ++nt)
                #pragma unroll
                for (int r = 0; r < 4; ++r) {
                    int row = mh * 64 + mt * 16 + quad * 4 + r;
                    float v = (noopf[row] != 0.0f) ? ev[nt] : fmaxf(acc[mt][nt][r], 0.f);
                    uet[row * 136 + ng * 32 + nt * 16 + l16] = f2u(v);
                }
    }
    __syncthreads();

    // ---- trunk: 4 N-chunks of 128; L1 (K=128, init=cse) -> L2 (nt=4) ----
    f32x4 acc2[4][4];                           // trunk L2: M=64 x N=64 / wave
    #pragma unroll
    for (int nt = 0; nt < 4; ++nt) {
        float bv = tb2[ng * 64 + nt * 16 + l16];
        #pragma unroll
        for (int mt = 0; mt < 4; ++mt) acc2[mt][nt] = {bv, bv, bv, bv};
    }

    for (int nc = 0; nc < 4; ++nc) {
        uint16_t* hw = (nc & 1) ? h1tb : h1ta;
        // ---- L1 chunk: M=128 x N=128, K=128; wave = M64 x N32 ----
        {
            f32x4 acc1[4][2];
            #pragma unroll
            for (int nt = 0; nt < 2; ++nt) {
                int n = nc * 128 + ng * 32 + nt * 16 + l16;
                #pragma unroll
                for (int mt = 0; mt < 4; ++mt) {
                    float v = u2f(cseL[(mh * 4 + mt) * 512 + n]);
                    acc1[mt][nt] = {v, v, v, v};
                }
            }
            const uint16_t* bb = tw1ue +
                (size_t)(nc * 128 + ng * 32 + l16) * 128 + quad * 8;
            bf16x8 bc[2], bn[2];
            bc[0] = *reinterpret_cast<const bf16x8*>(bb);
            bc[1] = *reinterpret_cast<const bf16x8*>(bb + 2048);
            #pragma unroll
            for (int kk = 0; kk < 4; ++kk) {
                if (kk < 3) {
                    bn[0] = *reinterpret_cast<const bf16x8*>(bb + (kk + 1) * 32);
                    bn[1] = *reinterpret_cast<const bf16x8*>(bb + 2048 + (kk + 1) * 32);
                }
                bf16x8 af[4];
                #pragma unroll
                for (int mt = 0; mt < 4; ++mt)
                    af[mt] = *reinterpret_cast<const bf16x8*>(
                        &uet[(mh * 64 + mt * 16 + l16) * 136 + kk * 32 + quad * 8]);
                #pragma unroll
                for (int mt = 0; mt < 4; ++mt)
                    #pragma unroll
                    for (int nt = 0; nt < 2; ++nt)
                        acc1[mt][nt] = __builtin_amdgcn_mfma_f32_16x16x32_bf16(
                            af[mt], bc[nt], acc1[mt][nt], 0, 0, 0);
                bc[0] = bn[0]; bc[1] = bn[1];
            }
            #pragma unroll
            for (int mt = 0; mt < 4; ++mt)
                #pragma unroll
                for (int nt = 0; nt < 2; ++nt)
                    #pragma unroll
                    for (int r = 0; r < 4; ++r) {
                        int row = mh * 64 + mt * 16 + quad * 4 + r;
                        hw[row * 136 + ng * 32 + nt * 16 + l16] =
                            f2u(fmaxf(acc1[mt][nt][r], 0.f));
                    }
        }
        __syncthreads();                        // hw ready (1 barrier/chunk)
        // ---- L2 accumulate: K-chunk 128; wave = M64 x N64 (nt=4) ----
        {
            const uint16_t* cb = tw2b + (size_t)(ng * 64 + l16) * 512 +
                                 nc * 128 + quad * 8;
            bf16x8 cc[4], cn[4];
            #pragma unroll
            for (int nt = 0; nt < 4; ++nt)
                cc[nt] = *reinterpret_cast<const bf16x8*>(cb + nt * 8192);
            #pragma unroll
            for (int k2 = 0; k2 < 4; ++k2) {
                if (k2 < 3) {
                    #pragma unroll
                    for (int nt = 0; nt < 4; ++nt)
                        cn[nt] = *reinterpret_cast<const bf16x8*>(
                            cb + nt * 8192 + (k2 + 1) * 32);
                }
                bf16x8 af[4];
                #pragma unroll
                for (int mt = 0; mt < 4; ++mt)
                    af[mt] = *reinterpret_cast<const bf16x8*>(
                        &hw[(mh * 64 + mt * 16 + l16) * 136 + k2 * 32 + quad * 8]);
                #pragma unroll
                for (int mt = 0; mt < 4; ++mt)
                    #pragma unroll
                    for (int nt = 0; nt < 4; ++nt)
                        acc2[mt][nt] = __builtin_amdgcn_mfma_f32_16x16x32_bf16(
                            af[mt], cc[nt], acc2[mt][nt], 0, 0, 0);
                #pragma unroll
                for (int nt = 0; nt < 4; ++nt) cc[nt] = cn[nt];
            }
        }
    }
    __syncthreads();                            // all hw reads done
    // ---- t2 epilogue (overlays uet + h1tA) ----
    #pragma unroll
    for (int mt = 0; mt < 4; ++mt)
        #pragma unroll
        for (int nt = 0; nt < 4; ++nt)
            #pragma unroll
            for (int r = 0; r < 4; ++r) {
                int row = mh * 64 + mt * 16 + quad * 4 + r;
                t2[row * 264 + ng * 64 + nt * 16 + l16] =
                    f2u(fmaxf(acc2[mt][nt][r], 0.f));
            }
    __syncthreads();

    // ---- heads: wave wv does rows 16wv..16wv+15 ----
    {
        float vwf[4], dwf[4];
        #pragma unroll
        for (int j = 0; j < 4; ++j) {
            vwf[j] = vw[lane + 64 * j];
            dwf[j] = dw[lane + 64 * j];
        }
        const float vbf = vb[0], dbf = db[0];
        #pragma unroll
        for (int rr = 0; rr < 16; ++rr) {
            int row = wv * 16 + rr;
            float sv = 0.f, sd = 0.f;
            #pragma unroll
            for (int j = 0; j < 4; ++j) {
                float tv = u2f(t2[row * 264 + lane + 64 * j]);
                sv += tv * vwf[j];
                sd += tv * dwf[j];
            }
            #pragma unroll
            for (int off = 32; off > 0; off >>= 1) {
                sv += __shfl_down(sv, off);
                sd += __shfl_down(sd, off);
            }
            if (lane == 0) {
                int g = blockIdx.x * 128 + row;
                out[g] = sv + vbf;
                float z = sd + dbf;
                float sig = 1.f / (1.f + __expf(-z));
                out[B_ * 16 + g] = sig * 0.4f + 0.1f;
            }
        }
    }
}

extern "C" void kernel_launch(void* const* d_in, const int* in_sizes, int n_in,
                              void* d_out, int out_size, void* d_ws, size_t ws_size,
                              hipStream_t stream) {
    const float* obs = (const float*)d_in[0];
    const float* sw1 = (const float*)d_in[1];
    const float* sb1 = (const float*)d_in[2];
    const float* sw2 = (const float*)d_in[3];
    const float* sb2 = (const float*)d_in[4];
    const float* uw1 = (const float*)d_in[5];
    const float* ub1 = (const float*)d_in[6];
    const float* uw2 = (const float*)d_in[7];
    const float* ub2 = (const float*)d_in[8];
    const float* emb = (const float*)d_in[9];
    const float* tw1 = (const float*)d_in[10];
    const float* tb1 = (const float*)d_in[11];
    const float* tw2 = (const float*)d_in[12];
    const float* tb2 = (const float*)d_in[13];
    const float* vw  = (const float*)d_in[14];
    const float* vb  = (const float*)d_in[15];
    const float* dw  = (const float*)d_in[16];
    const float* db  = (const float*)d_in[17];

    uint16_t* wsb = (uint16_t*)d_ws;

    k_conv<<<404, 256, 0, stream>>>(tw1, tw2, uw2, sw2, uw1, wsb);
    k_cse<<<256, 512, 0, stream>>>(obs, sw1, sb1, sb2, tb1, wsb);
    k_main<<<B_ / 8, 512, 0, stream>>>(obs, ub1, ub2, emb, tb2,
                                       vw, vb, dw, db, wsb, (float*)d_out);
}